// Round 1
// baseline (605.782 us; speedup 1.0000x reference)
//
#include <hip/hip_runtime.h>

// GCNConv forward: out = D^{-1/2} (A + I) D^{-1/2} (x @ W) + b
// N = 1,000,000 nodes, E = 4,000,000 edges, F = 16 features.
//
// Pipeline:
//   memset deg=0
//   K1: deg[col[e]] += 1                      (4M float atomics)
//   K2: h = x@W ; dinv = rsqrt(deg+1) ; out = h*dinv^2 + b   (1 thread/node)
//   K3: out[col] += h[row]*dinv[row]*dinv[col]               (1 thread per edge*feature)

#define F 16

__global__ void deg_kernel(const int* __restrict__ col, float* __restrict__ deg, int E) {
    int e = blockIdx.x * blockDim.x + threadIdx.x;
    if (e < E) {
        atomicAdd(&deg[col[e]], 1.0f);
    }
}

__global__ void node_kernel(const float* __restrict__ x, const float* __restrict__ W,
                            const float* __restrict__ b, float* __restrict__ deg_io,
                            float* __restrict__ h, float* __restrict__ out, int N) {
    __shared__ float sW[256];
    __shared__ float sb[16];
    if (threadIdx.x < 256) sW[threadIdx.x] = W[threadIdx.x];
    if (threadIdx.x < 16)  sb[threadIdx.x] = b[threadIdx.x];
    __syncthreads();

    int i = blockIdx.x * blockDim.x + threadIdx.x;
    if (i >= N) return;

    const float4* xr = (const float4*)(x + (size_t)i * F);
    float xv[16];
    #pragma unroll
    for (int q = 0; q < 4; q++) {
        float4 t = xr[q];
        xv[q*4+0] = t.x; xv[q*4+1] = t.y; xv[q*4+2] = t.z; xv[q*4+3] = t.w;
    }

    float hv[16];
    #pragma unroll
    for (int j = 0; j < 16; j++) {
        float acc = 0.0f;
        #pragma unroll
        for (int k = 0; k < 16; k++) acc += xv[k] * sW[k*16 + j];
        hv[j] = acc;
    }

    float4* hr = (float4*)(h + (size_t)i * F);
    #pragma unroll
    for (int q = 0; q < 4; q++)
        hr[q] = make_float4(hv[q*4+0], hv[q*4+1], hv[q*4+2], hv[q*4+3]);

    float di = rsqrtf(deg_io[i] + 1.0f);
    deg_io[i] = di;                 // deg array becomes dinv in-place
    float s = di * di;

    float4* orow = (float4*)(out + (size_t)i * F);
    #pragma unroll
    for (int q = 0; q < 4; q++)
        orow[q] = make_float4(hv[q*4+0]*s + sb[q*4+0], hv[q*4+1]*s + sb[q*4+1],
                              hv[q*4+2]*s + sb[q*4+2], hv[q*4+3]*s + sb[q*4+3]);
}

__global__ void scatter_kernel(const int* __restrict__ row, const int* __restrict__ col,
                               const float* __restrict__ dinv, const float* __restrict__ h,
                               float* __restrict__ out, int E) {
    int tid = blockIdx.x * blockDim.x + threadIdx.x;   // up to 64M, fits int32
    int e = tid >> 4;
    if (e >= E) return;
    int j = tid & 15;
    int r = row[e];
    int c = col[e];
    float norm = dinv[r] * dinv[c];
    atomicAdd(&out[(size_t)c * F + j], h[(size_t)r * F + j] * norm);
}

extern "C" void kernel_launch(void* const* d_in, const int* in_sizes, int n_in,
                              void* d_out, int out_size, void* d_ws, size_t ws_size,
                              hipStream_t stream) {
    const float* x  = (const float*)d_in[0];
    const int*   ei = (const int*)d_in[1];     // integer inputs passed as int32
    const float* W  = (const float*)d_in[2];
    const float* b  = (const float*)d_in[3];

    int N = in_sizes[0] / F;       // 1,000,000
    int E = in_sizes[1] / 2;       // 4,000,000
    const int* row = ei;           // edge_index[0] = src
    const int* col = ei + E;       // edge_index[1] = dst

    float* out = (float*)d_out;
    float* deg = (float*)d_ws;     // N floats; becomes dinv after node_kernel
    float* h   = deg + N;          // N*16 floats

    hipMemsetAsync(deg, 0, (size_t)N * sizeof(float), stream);

    deg_kernel<<<(E + 255) / 256, 256, 0, stream>>>(col, deg, E);

    node_kernel<<<(N + 255) / 256, 256, 0, stream>>>(x, W, b, deg, h, out, N);

    long long total = (long long)E * F;
    scatter_kernel<<<(int)((total + 255) / 256), 256, 0, stream>>>(row, col, deg, h, out, E);
}